// Round 1
// baseline (2274.061 us; speedup 1.0000x reference)
//
#include <hip/hip_runtime.h>
#include <hip/hip_bf16.h>
#include <math.h>

// Problem constants
#define BATCH 4
#define SEQ 2048
#define DMODEL 1024
#define NHEADS 16
#define DHEAD 64
#define MTOK (BATCH * SEQ)          // 8192 tokens
#define SCALE_Q 0.125f              // 1/sqrt(64)

// ---------------------------------------------------------------------------
// GEMM: C[M,N] = epilogue( sum_k A[m,k] * B[n,k] )   (NT: both row-major, K contiguous)
// mode 0: identity (with scale)    mode 1: phi(acc*scale) = elu+1
// Tiling: 64x64 block tile, BK=16, 256 threads, 4x4 micro-tile per thread.
// ---------------------------------------------------------------------------
#define TILE 64
#define BK 16

__global__ __launch_bounds__(256) void gemm_nt_ep(const float* __restrict__ A,
                                                  const float* __restrict__ B,
                                                  float* __restrict__ C,
                                                  int M, int N, int K,
                                                  int mode, float scale) {
    __shared__ float As[BK][TILE];   // [k][m]
    __shared__ float Bs[BK][TILE];   // [k][n]

    const int tid = threadIdx.x;
    const int m0 = blockIdx.y * TILE;
    const int n0 = blockIdx.x * TILE;

    // staging: thread loads one float4 of A and one of B
    const int lm = tid >> 2;            // 0..63  (row within tile)
    const int lk = (tid & 3) << 2;      // 0,4,8,12 (k within BK)
    const float* Aptr = A + (size_t)(m0 + lm) * K + lk;
    const float* Bptr = B + (size_t)(n0 + lm) * K + lk;

    // compute mapping: 4 rows x 4 cols per thread
    const int tm = (tid >> 4) << 2;     // 0..60
    const int tn = (tid & 15) << 2;     // 0..60

    float acc[4][4];
#pragma unroll
    for (int i = 0; i < 4; ++i)
#pragma unroll
        for (int j = 0; j < 4; ++j) acc[i][j] = 0.f;

    for (int k0 = 0; k0 < K; k0 += BK) {
        float4 av = *(const float4*)(Aptr + k0);
        float4 bv = *(const float4*)(Bptr + k0);
        __syncthreads();   // previous tile fully consumed
        As[lk + 0][lm] = av.x; As[lk + 1][lm] = av.y;
        As[lk + 2][lm] = av.z; As[lk + 3][lm] = av.w;
        Bs[lk + 0][lm] = bv.x; Bs[lk + 1][lm] = bv.y;
        Bs[lk + 2][lm] = bv.z; Bs[lk + 3][lm] = bv.w;
        __syncthreads();
#pragma unroll
        for (int kk = 0; kk < BK; ++kk) {
            float4 a = *(const float4*)&As[kk][tm];
            float4 b = *(const float4*)&Bs[kk][tn];
            acc[0][0] += a.x * b.x; acc[0][1] += a.x * b.y; acc[0][2] += a.x * b.z; acc[0][3] += a.x * b.w;
            acc[1][0] += a.y * b.x; acc[1][1] += a.y * b.y; acc[1][2] += a.y * b.z; acc[1][3] += a.y * b.w;
            acc[2][0] += a.z * b.x; acc[2][1] += a.z * b.y; acc[2][2] += a.z * b.z; acc[2][3] += a.z * b.w;
            acc[3][0] += a.w * b.x; acc[3][1] += a.w * b.y; acc[3][2] += a.w * b.z; acc[3][3] += a.w * b.w;
        }
    }

#pragma unroll
    for (int i = 0; i < 4; ++i) {
        float4 o;
        float r[4];
#pragma unroll
        for (int j = 0; j < 4; ++j) {
            float v = acc[i][j] * scale;
            if (mode == 1) v = (v > 0.f) ? (v + 1.f) : __expf(v);  // elu(v)+1
            r[j] = v;
        }
        o.x = r[0]; o.y = r[1]; o.z = r[2]; o.w = r[3];
        *(float4*)&C[(size_t)(m0 + tm + i) * N + (n0 + tn)] = o;
    }
}

// ---------------------------------------------------------------------------
// Gate: gate[m][h] = sigmoid( sum_k x[m][k] * Wg[h][k] + bg[h] )
// One block per token; 16 threads per head; shuffle-reduce within 16 lanes.
// ---------------------------------------------------------------------------
__global__ __launch_bounds__(256) void gate_kernel(const float* __restrict__ x,
                                                   const float* __restrict__ Wg,
                                                   const float* __restrict__ bg,
                                                   float* __restrict__ gate) {
    const int m = blockIdx.x;           // token
    const int tid = threadIdx.x;
    const int h = tid >> 4;             // 0..15
    const int r = tid & 15;             // 0..15

    const float* xr = x + (size_t)m * DMODEL;
    const float* wr = Wg + (size_t)h * DMODEL;

    float p = 0.f;
#pragma unroll
    for (int i = 0; i < 16; ++i) {
        const int k = (r << 2) + (i << 6);        // r*4 + i*64 covers [0,1024)
        float4 xv = *(const float4*)&xr[k];
        float4 wv = *(const float4*)&wr[k];
        p += xv.x * wv.x + xv.y * wv.y + xv.z * wv.z + xv.w * wv.w;
    }
    // reduce over the 16 lanes of this head (lanes h*16 .. h*16+15 within wave)
    p += __shfl_xor(p, 8, 64);
    p += __shfl_xor(p, 4, 64);
    p += __shfl_xor(p, 2, 64);
    p += __shfl_xor(p, 1, 64);
    if (r == 0) {
        float v = p + bg[h];
        gate[(size_t)m * NHEADS + h] = 1.f / (1.f + __expf(-v));
    }
}

// ---------------------------------------------------------------------------
// Recurrence: one block per (b,h) chain. S[64][64] in registers:
// thread (wave w, lane l): owns S[i][j] for j = w*16 + (l&15), i in (l>>4)*16 .. +15.
// Double-buffered LDS staging of (q,k,v,g) per timestep, 1 barrier/step.
// y_t[j] = sum_i q_t[i] * S_t[i][j],  S_t = g_t*S_{t-1} + k_t (x) v_t
// ---------------------------------------------------------------------------
__global__ __launch_bounds__(256) void recur_kernel(const float* __restrict__ q,
                                                    const float* __restrict__ k,
                                                    const float* __restrict__ v,
                                                    const float* __restrict__ gate,
                                                    float* __restrict__ y) {
    const int chain = blockIdx.x;       // 0..63
    const int b = chain >> 4;
    const int h = chain & 15;
    const int tid = threadIdx.x;
    const int w = tid >> 6;             // wave 0..3
    const int l = tid & 63;
    const int j = (w << 4) | (l & 15);  // 0..63 column owned
    const int i0 = (l >> 4) << 4;       // 0,16,32,48 row-group base

    __shared__ float buf[2][208];       // [q:0..63][k:64..127][v:128..191][g:192]

    float s[16];
#pragma unroll
    for (int r = 0; r < 16; ++r) s[r] = 0.f;

    const size_t base0 = ((size_t)b * SEQ) * DMODEL + (size_t)h * DHEAD;

    // stage t = 0
    if (tid < 64)       buf[0][tid]        = q[base0 + tid];
    else if (tid < 128) buf[0][tid]        = k[base0 + (tid - 64)];
    else if (tid < 192) buf[0][tid]        = v[base0 + (tid - 128)];
    else if (tid == 192) buf[0][192] = gate[((size_t)b * SEQ) * NHEADS + h];

    for (int t = 0; t < SEQ; ++t) {
        __syncthreads();                 // buf[t&1] staged; buf[(t+1)&1] free
        const float* bp = buf[t & 1];
        const float g  = bp[192];
        const float vj = bp[128 + j];
        float p = 0.f;
#pragma unroll
        for (int r = 0; r < 16; r += 4) {
            float4 k4 = *(const float4*)&bp[64 + i0 + r];
            float4 q4 = *(const float4*)&bp[i0 + r];
            s[r + 0] = g * s[r + 0] + k4.x * vj;  p += q4.x * s[r + 0];
            s[r + 1] = g * s[r + 1] + k4.y * vj;  p += q4.y * s[r + 1];
            s[r + 2] = g * s[r + 2] + k4.z * vj;  p += q4.z * s[r + 2];
            s[r + 3] = g * s[r + 3] + k4.w * vj;  p += q4.w * s[r + 3];
        }
        // stage next step while reduction happens
        if (t + 1 < SEQ) {
            const size_t baseN = base0 + (size_t)(t + 1) * DMODEL;
            float* nb = buf[(t + 1) & 1];
            if (tid < 64)       nb[tid] = q[baseN + tid];
            else if (tid < 128) nb[tid] = k[baseN + (tid - 64)];
            else if (tid < 192) nb[tid] = v[baseN + (tid - 128)];
            else if (tid == 192) nb[192] = gate[((size_t)b * SEQ + (t + 1)) * NHEADS + h];
        }
        // reduce partials across the 4 row-groups (lanes l, l^16, l^32, l^48)
        p += __shfl_xor(p, 16, 64);
        p += __shfl_xor(p, 32, 64);
        if (l < 16) y[base0 + (size_t)t * DMODEL + (w << 4) + l] = p;
    }
}

// ---------------------------------------------------------------------------
// Host launch
// ---------------------------------------------------------------------------
extern "C" void kernel_launch(void* const* d_in, const int* in_sizes, int n_in,
                              void* d_out, int out_size, void* d_ws, size_t ws_size,
                              hipStream_t stream) {
    const float* x  = (const float*)d_in[0];
    const float* Wq = (const float*)d_in[1];
    const float* Wk = (const float*)d_in[2];
    const float* Wv = (const float*)d_in[3];
    const float* Wo = (const float*)d_in[4];
    const float* Wg = (const float*)d_in[5];
    const float* bg = (const float*)d_in[6];
    float* out = (float*)d_out;

    const size_t elems = (size_t)MTOK * DMODEL;           // 8,388,608
    const size_t need = (4 * elems + (size_t)MTOK * NHEADS) * sizeof(float);
    if (ws_size < need) return;   // insufficient scratch — fail visibly

    float* q    = (float*)d_ws;
    float* k    = q + elems;
    float* v    = k + elems;
    float* y    = v + elems;
    float* gate = y + elems;

    dim3 gridG(DMODEL / TILE, MTOK / TILE);   // (16, 128)
    dim3 blockG(256);

    // projections with fused feature map
    gemm_nt_ep<<<gridG, blockG, 0, stream>>>(x, Wq, q, MTOK, DMODEL, DMODEL, 1, SCALE_Q);
    gemm_nt_ep<<<gridG, blockG, 0, stream>>>(x, Wk, k, MTOK, DMODEL, DMODEL, 1, 1.0f);
    gemm_nt_ep<<<gridG, blockG, 0, stream>>>(x, Wv, v, MTOK, DMODEL, DMODEL, 0, 1.0f);

    gate_kernel<<<dim3(MTOK), dim3(256), 0, stream>>>(x, Wg, bg, gate);

    recur_kernel<<<dim3(BATCH * NHEADS), dim3(256), 0, stream>>>(q, k, v, gate, y);

    // output projection
    gemm_nt_ep<<<gridG, blockG, 0, stream>>>(y, Wo, out, MTOK, DMODEL, DMODEL, 0, 1.0f);
}

// Round 4
// 774.194 us; speedup vs baseline: 2.9373x; 2.9373x over previous
//
#include <hip/hip_runtime.h>
#include <hip/hip_bf16.h>
#include <math.h>

// Problem constants
#define BATCH 4
#define SEQ 2048
#define DMODEL 1024
#define NHEADS 16
#define DHEAD 64
#define MTOK (BATCH * SEQ)          // 8192 tokens
#define SCALE_Q 0.125f              // 1/sqrt(64)

typedef unsigned short ushort_t;
typedef __attribute__((ext_vector_type(8))) short bf16x8;   // 8 bf16 in 4 VGPRs
typedef __attribute__((ext_vector_type(4))) float f32x4;

__device__ __forceinline__ float bf2f(unsigned short u) {
    return __uint_as_float(((unsigned)u) << 16);
}
__device__ __forceinline__ unsigned short f2bf(float f) {
    unsigned u = __float_as_uint(f);
    return (unsigned short)((u + 0x7fffu + ((u >> 16) & 1u)) >> 16);  // RNE
}

// ---------------------------------------------------------------------------
// fp32 -> bf16 elementwise convert (float4 in, ushort4 out)
// ---------------------------------------------------------------------------
__global__ __launch_bounds__(256) void cvt_f32_bf16(const float* __restrict__ in,
                                                    ushort_t* __restrict__ out, int n4) {
    int i = blockIdx.x * 256 + threadIdx.x;
    if (i < n4) {
        float4 v = ((const float4*)in)[i];
        ushort4 o;
        o.x = f2bf(v.x); o.y = f2bf(v.y); o.z = f2bf(v.z); o.w = f2bf(v.w);
        ((ushort4*)out)[i] = o;
    }
}

// ---------------------------------------------------------------------------
// bf16 MFMA GEMM (m97 structure): C[M,N] = ep( A[M,K] @ B[N,K]^T )
// 128x128 tile, BK=32, 256 thr = 4 waves, each wave 64x64 via 4x4 of 16x16x32.
// Staging: global_load_lds width=16, wave-uniform LDS base + lane*16 (no pad).
// mode 0: identity -> fp32 Cf    mode 1: phi(acc*scale) -> bf16 Cb
// mode 2: identity -> bf16 Cb
// ---------------------------------------------------------------------------
#define GT 128
#define GBK 32

__global__ __launch_bounds__(256) void gemm_bf16(const ushort_t* __restrict__ A,
                                                 const ushort_t* __restrict__ B,
                                                 float* __restrict__ Cf,
                                                 ushort_t* __restrict__ Cb,
                                                 int M, int N, int K,
                                                 int mode, float scale) {
    __shared__ ushort_t As[GT * GBK];   // [row][k] k-contiguous, no pad (DMA constraint)
    __shared__ ushort_t Bs[GT * GBK];

    const int tid = threadIdx.x;
    const int w = tid >> 6;             // wave 0..3
    const int l = tid & 63;
    const int m0 = blockIdx.y * GT;
    const int n0 = blockIdx.x * GT;
    const int wm = (w >> 1) * 64;       // wave row offset in tile
    const int wn = (w & 1) * 64;        // wave col offset in tile

    // staging map: lane l covers row l>>2 (of a 16-row segment), 16B chunk l&3
    const int srow = l >> 2;
    const int schunk = (l & 3) * 8;     // bf16 elements

    f32x4 acc[4][4];
#pragma unroll
    for (int i = 0; i < 4; ++i)
#pragma unroll
        for (int j = 0; j < 4; ++j)
#pragma unroll
            for (int r = 0; r < 4; ++r) acc[i][j][r] = 0.f;

    const int fr = l & 15;              // fragment row (A) / col (B)
    const int fq = (l >> 4) * 8;        // fragment k-offset

    for (int k0 = 0; k0 < K; k0 += GBK) {
        __syncthreads();                // all waves done reading LDS (prev iter)
#pragma unroll
        for (int i = 0; i < 2; ++i) {
            const int s = w * 2 + i;    // segment 0..7 -> rows s*16..s*16+15
            const ushort_t* ga = A + (size_t)(m0 + s * 16 + srow) * K + k0 + schunk;
            const ushort_t* gb = B + (size_t)(n0 + s * 16 + srow) * K + k0 + schunk;
            __builtin_amdgcn_global_load_lds(
                (const __attribute__((address_space(1))) unsigned int*)(const void*)ga,
                (__attribute__((address_space(3))) unsigned int*)(void*)&As[s * 16 * GBK],
                16, 0, 0);
            __builtin_amdgcn_global_load_lds(
                (const __attribute__((address_space(1))) unsigned int*)(const void*)gb,
                (__attribute__((address_space(3))) unsigned int*)(void*)&Bs[s * 16 * GBK],
                16, 0, 0);
        }
        __syncthreads();                // staging landed (vmcnt drained by barrier)

        bf16x8 af[4], bfr[4];
#pragma unroll
        for (int ti = 0; ti < 4; ++ti)
            af[ti] = *(const bf16x8*)&As[(wm + ti * 16 + fr) * GBK + fq];
#pragma unroll
        for (int tj = 0; tj < 4; ++tj)
            bfr[tj] = *(const bf16x8*)&Bs[(wn + tj * 16 + fr) * GBK + fq];
#pragma unroll
        for (int ti = 0; ti < 4; ++ti)
#pragma unroll
            for (int tj = 0; tj < 4; ++tj)
                acc[ti][tj] = __builtin_amdgcn_mfma_f32_16x16x32_bf16(
                    af[ti], bfr[tj], acc[ti][tj], 0, 0, 0);
    }

    // epilogue: C/D layout col=lane&15, row=(lane>>4)*4+reg
    const int er = (l >> 4) * 4;
    const int ec = l & 15;
#pragma unroll
    for (int ti = 0; ti < 4; ++ti)
#pragma unroll
        for (int tj = 0; tj < 4; ++tj)
#pragma unroll
            for (int r = 0; r < 4; ++r) {
                const int row = m0 + wm + ti * 16 + er + r;
                const int col = n0 + wn + tj * 16 + ec;
                float val = acc[ti][tj][r] * scale;
                if (mode == 1) val = (val > 0.f) ? (val + 1.f) : __expf(val);  // elu+1
                if (mode == 0) Cf[(size_t)row * N + col] = val;
                else           Cb[(size_t)row * N + col] = f2bf(val);
            }
}

// ---------------------------------------------------------------------------
// Gate: gate[m][h] = sigmoid( sum_k x[m][k] * Wg[h][k] + bg[h] )   (fp32)
// ---------------------------------------------------------------------------
__global__ __launch_bounds__(256) void gate_kernel(const float* __restrict__ x,
                                                   const float* __restrict__ Wg,
                                                   const float* __restrict__ bg,
                                                   float* __restrict__ gate) {
    const int m = blockIdx.x;
    const int tid = threadIdx.x;
    const int h = tid >> 4;
    const int r = tid & 15;

    const float* xr = x + (size_t)m * DMODEL;
    const float* wr = Wg + (size_t)h * DMODEL;

    float p = 0.f;
#pragma unroll
    for (int i = 0; i < 16; ++i) {
        const int k = (r << 2) + (i << 6);
        float4 xv = *(const float4*)&xr[k];
        float4 wv = *(const float4*)&wr[k];
        p += xv.x * wv.x + xv.y * wv.y + xv.z * wv.z + xv.w * wv.w;
    }
    p += __shfl_xor(p, 8, 64);
    p += __shfl_xor(p, 4, 64);
    p += __shfl_xor(p, 2, 64);
    p += __shfl_xor(p, 1, 64);
    if (r == 0) {
        float vv = p + bg[h];
        gate[(size_t)m * NHEADS + h] = 1.f / (1.f + __expf(-vv));
    }
}

// ---------------------------------------------------------------------------
// Recurrence: chunked LDS staging (bf16 q/k/v, fp32 scan state, bf16 y out).
// Grid: 128 blocks = 64 chains x 2 column-halves. Block = 4 waves.
// Wave w owns cols jrel = w*8+(l&7); thread owns rows i0=(l>>3)*8..+7.
// No __syncthreads within a chunk (wave-local LDS broadcasts + xor-shuffle).
// ---------------------------------------------------------------------------
#define CHUNK 32
#define COLS 32
#define NCHUNK (SEQ / CHUNK)

__global__ __launch_bounds__(256) void recur_kernel(const ushort_t* __restrict__ q,
                                                    const ushort_t* __restrict__ k,
                                                    const ushort_t* __restrict__ v,
                                                    const float* __restrict__ gate,
                                                    ushort_t* __restrict__ y) {
    const int blk = blockIdx.x;          // 0..127
    const int chain = blk >> 1;
    const int half = blk & 1;
    const int b = chain >> 4;
    const int h = chain & 15;
    const int tid = threadIdx.x;
    const int w = tid >> 6;
    const int l = tid & 63;
    const int jrel = (w << 3) | (l & 7); // 0..31 col within block
    const int i0 = (l >> 3) << 3;        // 0,8,..,56 row base

    __shared__ ushort_t qs[2][CHUNK * 64];
    __shared__ ushort_t ks[2][CHUNK * 64];
    __shared__ ushort_t vs[2][CHUNK * COLS];
    __shared__ float gs[2][CHUNK];

    const size_t baseqk = ((size_t)b * SEQ) * DMODEL + (size_t)h * DHEAD;
    const size_t basev  = baseqk + (size_t)half * COLS;
    const size_t baseg  = (size_t)b * SEQ * NHEADS + h;

    // staging: 8 lanes per timestep; each lane loads 16B (8 bf16)
    const int sstep = tid >> 3;          // 0..31 timestep in chunk
    const int soff  = (tid & 7) << 3;    // q/k bf16 offset 0..56
    const bool vpart = (tid & 7) < 4;    // 4 lanes cover v's 32 bf16
    const int voff  = (tid & 3) << 3;

    float s[8];
#pragma unroll
    for (int r = 0; r < 8; ++r) s[r] = 0.f;

    float4 rq, rk, rv;
    float rg = 0.f;

    // load + stage chunk 0
    {
        const size_t row = baseqk + (size_t)sstep * DMODEL;
        rq = *(const float4*)&q[row + soff];
        rk = *(const float4*)&k[row + soff];
        if (vpart) rv = *(const float4*)&v[basev + (size_t)sstep * DMODEL + voff];
        if (tid < CHUNK) rg = gate[baseg + (size_t)tid * NHEADS];

        *(float4*)&qs[0][sstep * 64 + soff] = rq;
        *(float4*)&ks[0][sstep * 64 + soff] = rk;
        if (vpart) *(float4*)&vs[0][sstep * COLS + voff] = rv;
        if (tid < CHUNK) gs[0][tid] = rg;
    }
    __syncthreads();

    for (int c = 0; c < NCHUNK; ++c) {
        // prefetch chunk c+1 into registers (overlapped with compute)
        if (c + 1 < NCHUNK) {
            const size_t row = baseqk + (size_t)((c + 1) * CHUNK + sstep) * DMODEL;
            rq = *(const float4*)&q[row + soff];
            rk = *(const float4*)&k[row + soff];
            if (vpart) rv = *(const float4*)&v[basev + (size_t)((c + 1) * CHUNK + sstep) * DMODEL + voff];
            if (tid < CHUNK) rg = gate[baseg + (size_t)((c + 1) * CHUNK + tid) * NHEADS];
        }

        const ushort_t* __restrict__ qb = qs[c & 1];
        const ushort_t* __restrict__ kb = ks[c & 1];
        const ushort_t* __restrict__ vb = vs[c & 1];
        const float* __restrict__ gb = gs[c & 1];

        ushort_t* yptr = y + baseqk + (size_t)(c * CHUNK) * DMODEL
                           + (size_t)half * COLS + (w << 3) + l;   // valid when l<8

#pragma unroll 8
        for (int t = 0; t < CHUNK; ++t) {
            const float g  = gb[t];
            const float vj = bf2f(vb[t * COLS + jrel]);
            union { float4 f4; unsigned short us[8]; } uq, uk;
            uq.f4 = *(const float4*)&qb[t * 64 + i0];
            uk.f4 = *(const float4*)&kb[t * 64 + i0];
            float p = 0.f;
#pragma unroll
            for (int r = 0; r < 8; ++r) {
                s[r] = g * s[r] + bf2f(uk.us[r]) * vj;
                p += bf2f(uq.us[r]) * s[r];
            }
            p += __shfl_xor(p, 8, 64);
            p += __shfl_xor(p, 16, 64);
            p += __shfl_xor(p, 32, 64);
            if (l < 8) yptr[(size_t)t * DMODEL] = f2bf(p);
        }

        if (c + 1 < NCHUNK) {
            const int nb = (c + 1) & 1;
            *(float4*)&qs[nb][sstep * 64 + soff] = rq;
            *(float4*)&ks[nb][sstep * 64 + soff] = rk;
            if (vpart) *(float4*)&vs[nb][sstep * COLS + voff] = rv;
            if (tid < CHUNK) gs[nb][tid] = rg;
        }
        __syncthreads();
    }
}

// ---------------------------------------------------------------------------
// Host launch
// ---------------------------------------------------------------------------
extern "C" void kernel_launch(void* const* d_in, const int* in_sizes, int n_in,
                              void* d_out, int out_size, void* d_ws, size_t ws_size,
                              hipStream_t stream) {
    const float* x  = (const float*)d_in[0];
    const float* Wq = (const float*)d_in[1];
    const float* Wk = (const float*)d_in[2];
    const float* Wv = (const float*)d_in[3];
    const float* Wo = (const float*)d_in[4];
    const float* Wg = (const float*)d_in[5];
    const float* bg = (const float*)d_in[6];
    float* out = (float*)d_out;

    const size_t elems = (size_t)MTOK * DMODEL;     // 8,388,608
    const size_t welems = (size_t)DMODEL * DMODEL;  // 1,048,576

    // workspace layout (bf16 buffers then fp32 gate)
    const size_t need = (5 * elems + 4 * welems) * sizeof(ushort_t)
                      + (size_t)MTOK * NHEADS * sizeof(float);     // ~92.8 MB
    if (ws_size < need) return;

    ushort_t* xb  = (ushort_t*)d_ws;
    ushort_t* qb  = xb + elems;
    ushort_t* kb  = qb + elems;
    ushort_t* vb  = kb + elems;
    ushort_t* yb  = vb + elems;
    ushort_t* wqb = yb + elems;
    ushort_t* wkb = wqb + welems;
    ushort_t* wvb = wkb + welems;
    ushort_t* wob = wvb + welems;
    float* gate   = (float*)(wob + welems);

    // converts
    cvt_f32_bf16<<<dim3((int)(elems / 4 / 256)), dim3(256), 0, stream>>>(x, xb, (int)(elems / 4));
    cvt_f32_bf16<<<dim3((int)(welems / 4 / 256)), dim3(256), 0, stream>>>(Wq, wqb, (int)(welems / 4));
    cvt_f32_bf16<<<dim3((int)(welems / 4 / 256)), dim3(256), 0, stream>>>(Wk, wkb, (int)(welems / 4));
    cvt_f32_bf16<<<dim3((int)(welems / 4 / 256)), dim3(256), 0, stream>>>(Wv, wvb, (int)(welems / 4));
    cvt_f32_bf16<<<dim3((int)(welems / 4 / 256)), dim3(256), 0, stream>>>(Wo, wob, (int)(welems / 4));

    dim3 gridG(DMODEL / GT, MTOK / GT);   // (8, 64)
    dim3 blockG(256);

    // projections with fused feature map (bf16 outputs)
    gemm_bf16<<<gridG, blockG, 0, stream>>>(xb, wqb, nullptr, qb, MTOK, DMODEL, DMODEL, 1, SCALE_Q);
    gemm_bf16<<<gridG, blockG, 0, stream>>>(xb, wkb, nullptr, kb, MTOK, DMODEL, DMODEL, 1, 1.0f);
    gemm_bf16<<<gridG, blockG, 0, stream>>>(xb, wvb, nullptr, vb, MTOK, DMODEL, DMODEL, 2, 1.0f);

    gate_kernel<<<dim3(MTOK), dim3(256), 0, stream>>>(x, Wg, bg, gate);

    recur_kernel<<<dim3(2 * BATCH * NHEADS), dim3(256), 0, stream>>>(qb, kb, vb, gate, yb);

    // output projection (fp32 out)
    gemm_bf16<<<gridG, blockG, 0, stream>>>(yb, wob, out, nullptr, MTOK, DMODEL, DMODEL, 0, 1.0f);
}

// Round 5
// 318.980 us; speedup vs baseline: 7.1292x; 2.4271x over previous
//
#include <hip/hip_runtime.h>
#include <hip/hip_bf16.h>
#include <math.h>

// Problem constants
#define BATCH 4
#define SEQ 2048
#define DMODEL 1024
#define NHEADS 16
#define DHEAD 64
#define MTOK (BATCH * SEQ)          // 8192 tokens
#define SCALE_Q 0.125f              // 1/sqrt(64)
#define NCHAIN (BATCH * NHEADS)     // 64
#define CT 64                       // chunk length (timesteps)
#define NC (SEQ / CT)               // 32 chunks per chain
#define SP 72                       // padded LDS row stride (ushorts); 144B = 9*16 aligned

typedef unsigned short ushort_t;
typedef __attribute__((ext_vector_type(8))) short bf16x8;   // 8 bf16 in 4 VGPRs
typedef __attribute__((ext_vector_type(4))) float f32x4;

__device__ __forceinline__ float bf2f(unsigned short u) {
    return __uint_as_float(((unsigned)u) << 16);
}
__device__ __forceinline__ unsigned short f2bf(float f) {
    unsigned u = __float_as_uint(f);
    return (unsigned short)((u + 0x7fffu + ((u >> 16) & 1u)) >> 16);  // RNE
}

// ---------------------------------------------------------------------------
// fp32 -> bf16 elementwise convert
// ---------------------------------------------------------------------------
__global__ __launch_bounds__(256) void cvt_f32_bf16(const float* __restrict__ in,
                                                    ushort_t* __restrict__ out, int n4) {
    int i = blockIdx.x * 256 + threadIdx.x;
    if (i < n4) {
        float4 v = ((const float4*)in)[i];
        ushort4 o;
        o.x = f2bf(v.x); o.y = f2bf(v.y); o.z = f2bf(v.z); o.w = f2bf(v.w);
        ((ushort4*)out)[i] = o;
    }
}

// ---------------------------------------------------------------------------
// bf16 MFMA GEMM (m97 structure): C[M,N] = ep( A[M,K] @ B[N,K]^T )
// mode 0: identity -> fp32 Cf    mode 1: phi(acc*scale) -> bf16 Cb
// mode 2: identity -> bf16 Cb
// ---------------------------------------------------------------------------
#define GT 128
#define GBK 32

__global__ __launch_bounds__(256) void gemm_bf16(const ushort_t* __restrict__ A,
                                                 const ushort_t* __restrict__ B,
                                                 float* __restrict__ Cf,
                                                 ushort_t* __restrict__ Cb,
                                                 int M, int N, int K,
                                                 int mode, float scale) {
    __shared__ ushort_t As[GT * GBK];   // [row][k] k-contiguous, no pad (DMA constraint)
    __shared__ ushort_t Bs[GT * GBK];

    const int tid = threadIdx.x;
    const int w = tid >> 6;
    const int l = tid & 63;
    const int m0 = blockIdx.y * GT;
    const int n0 = blockIdx.x * GT;
    const int wm = (w >> 1) * 64;
    const int wn = (w & 1) * 64;

    const int srow = l >> 2;
    const int schunk = (l & 3) * 8;

    f32x4 acc[4][4];
#pragma unroll
    for (int i = 0; i < 4; ++i)
#pragma unroll
        for (int j = 0; j < 4; ++j)
#pragma unroll
            for (int r = 0; r < 4; ++r) acc[i][j][r] = 0.f;

    const int fr = l & 15;
    const int fq = (l >> 4) * 8;

    for (int k0 = 0; k0 < K; k0 += GBK) {
        __syncthreads();
#pragma unroll
        for (int i = 0; i < 2; ++i) {
            const int s = w * 2 + i;
            const ushort_t* ga = A + (size_t)(m0 + s * 16 + srow) * K + k0 + schunk;
            const ushort_t* gb = B + (size_t)(n0 + s * 16 + srow) * K + k0 + schunk;
            __builtin_amdgcn_global_load_lds(
                (const __attribute__((address_space(1))) unsigned int*)(const void*)ga,
                (__attribute__((address_space(3))) unsigned int*)(void*)&As[s * 16 * GBK],
                16, 0, 0);
            __builtin_amdgcn_global_load_lds(
                (const __attribute__((address_space(1))) unsigned int*)(const void*)gb,
                (__attribute__((address_space(3))) unsigned int*)(void*)&Bs[s * 16 * GBK],
                16, 0, 0);
        }
        __syncthreads();

        bf16x8 af[4], bfr[4];
#pragma unroll
        for (int ti = 0; ti < 4; ++ti)
            af[ti] = *(const bf16x8*)&As[(wm + ti * 16 + fr) * GBK + fq];
#pragma unroll
        for (int tj = 0; tj < 4; ++tj)
            bfr[tj] = *(const bf16x8*)&Bs[(wn + tj * 16 + fr) * GBK + fq];
#pragma unroll
        for (int ti = 0; ti < 4; ++ti)
#pragma unroll
            for (int tj = 0; tj < 4; ++tj)
                acc[ti][tj] = __builtin_amdgcn_mfma_f32_16x16x32_bf16(
                    af[ti], bfr[tj], acc[ti][tj], 0, 0, 0);
    }

    const int er = (l >> 4) * 4;
    const int ec = l & 15;
#pragma unroll
    for (int ti = 0; ti < 4; ++ti)
#pragma unroll
        for (int tj = 0; tj < 4; ++tj)
#pragma unroll
            for (int r = 0; r < 4; ++r) {
                const int row = m0 + wm + ti * 16 + er + r;
                const int col = n0 + wn + tj * 16 + ec;
                float val = acc[ti][tj][r] * scale;
                if (mode == 1) val = (val > 0.f) ? (val + 1.f) : __expf(val);  // elu+1
                if (mode == 0) Cf[(size_t)row * N + col] = val;
                else           Cb[(size_t)row * N + col] = f2bf(val);
            }
}

// ---------------------------------------------------------------------------
// Gate: gate[m][h] = sigmoid( sum_k x[m][k] * Wg[h][k] + bg[h] )   (fp32)
// ---------------------------------------------------------------------------
__global__ __launch_bounds__(256) void gate_kernel(const float* __restrict__ x,
                                                   const float* __restrict__ Wg,
                                                   const float* __restrict__ bg,
                                                   float* __restrict__ gate) {
    const int m = blockIdx.x;
    const int tid = threadIdx.x;
    const int h = tid >> 4;
    const int r = tid & 15;

    const float* xr = x + (size_t)m * DMODEL;
    const float* wr = Wg + (size_t)h * DMODEL;

    float p = 0.f;
#pragma unroll
    for (int i = 0; i < 16; ++i) {
        const int k = (r << 2) + (i << 6);
        float4 xv = *(const float4*)&xr[k];
        float4 wv = *(const float4*)&wr[k];
        p += xv.x * wv.x + xv.y * wv.y + xv.z * wv.z + xv.w * wv.w;
    }
    p += __shfl_xor(p, 8, 64);
    p += __shfl_xor(p, 4, 64);
    p += __shfl_xor(p, 2, 64);
    p += __shfl_xor(p, 1, 64);
    if (r == 0) {
        float vv = p + bg[h];
        gate[(size_t)m * NHEADS + h] = 1.f / (1.f + __expf(-vv));
    }
}

// ---------------------------------------------------------------------------
// Phase 1: per (chain, chunk) tile, compute decay-weighted KV outer-product sum
//   Dt[j][i] = sum_tau e^{b63 - b_tau} * v[tau][j] * k[tau][i]   (= D^T, fp32)
// and Bg[tile] = b63 (log of total chunk decay).
// MFMA: m=j (A = V^T, u16-gathered), n=i (B = K' with decay, u16-gathered), k=tau.
// ---------------------------------------------------------------------------
__global__ __launch_bounds__(256) void p1_kernel(const ushort_t* __restrict__ kb,
                                                 const ushort_t* __restrict__ vb,
                                                 const float* __restrict__ gate,
                                                 float* __restrict__ Dt,
                                                 float* __restrict__ Bg) {
    const int tile = blockIdx.x;          // 0..2047
    const int chain = tile >> 5;
    const int c = tile & 31;
    const int b = chain >> 4;
    const int h = chain & 15;
    const int tid = threadIdx.x;
    const int w = tid >> 6;
    const int l = tid & 63;

    __shared__ ushort_t Ks[CT * SP];
    __shared__ ushort_t Vs[CT * SP];
    __shared__ float bs[CT];

    // stage K,V chunk: thread -> row tid>>2 (t), 16 cols at (tid&3)*16
    {
        const int row = tid >> 2;
        const int seg = (tid & 3) * 16;
        const size_t grow = ((size_t)(b * SEQ + c * CT + row)) * DMODEL + h * DHEAD + seg;
        float4 a0 = *(const float4*)&kb[grow];
        float4 a1 = *(const float4*)&kb[grow + 8];
        float4 b0 = *(const float4*)&vb[grow];
        float4 b1 = *(const float4*)&vb[grow + 8];
        *(float4*)&Ks[row * SP + seg]     = a0;
        *(float4*)&Ks[row * SP + seg + 8] = a1;
        *(float4*)&Vs[row * SP + seg]     = b0;
        *(float4*)&Vs[row * SP + seg + 8] = b1;
    }
    // cumulative log-gate (wave 0)
    if (tid < 64) {
        float g = gate[((size_t)(b * SEQ + c * CT + tid)) * NHEADS + h];
        float lg = __logf(g);
#pragma unroll
        for (int d = 1; d < 64; d <<= 1) {
            float n = __shfl_up(lg, d, 64);
            if (l >= d) lg += n;
        }
        bs[tid] = lg;
        if (tid == 63) Bg[tile] = lg;
    }
    __syncthreads();

    const float B = bs[63];
    const int fr = l & 15;
    const int fq = (l >> 4) * 8;
    const int jw = w * 16;

    f32x4 accD[4];
#pragma unroll
    for (int nt = 0; nt < 4; ++nt)
#pragma unroll
        for (int r = 0; r < 4; ++r) accD[nt][r] = 0.f;

#pragma unroll
    for (int kc = 0; kc < 2; ++kc) {
        float ef[8];
#pragma unroll
        for (int m = 0; m < 8; ++m) ef[m] = __expf(B - bs[kc * 32 + fq + m]);
        bf16x8 va;
#pragma unroll
        for (int m = 0; m < 8; ++m)
            va[m] = (short)Vs[(kc * 32 + fq + m) * SP + jw + fr];
#pragma unroll
        for (int nt = 0; nt < 4; ++nt) {
            bf16x8 kf;
#pragma unroll
            for (int m = 0; m < 8; ++m)
                kf[m] = (short)f2bf(ef[m] * bf2f(Ks[(kc * 32 + fq + m) * SP + nt * 16 + fr]));
            accD[nt] = __builtin_amdgcn_mfma_f32_16x16x32_bf16(va, kf, accD[nt], 0, 0, 0);
        }
    }

    const int er = (l >> 4) * 4;
    const size_t dbase = (size_t)tile * (DHEAD * DHEAD);
#pragma unroll
    for (int nt = 0; nt < 4; ++nt)
#pragma unroll
        for (int r = 0; r < 4; ++r) {
            const int j = jw + er + r;
            const int i = nt * 16 + fr;
            Dt[dbase + j * DHEAD + i] = accD[nt][r];
        }
}

// ---------------------------------------------------------------------------
// Phase 2: sequential (over 32 chunks) state recurrence, parallel over
// 64 chains x 4096 elements.  St[c] = S before chunk c (bf16, stored [j][i]).
//   S <- e^{B_c} * S + Dt_c
// Grid: 256 blocks (chain x 4 j-quarters), 256 threads, 4 elements each.
// ---------------------------------------------------------------------------
__global__ __launch_bounds__(256) void p2_kernel(const float* __restrict__ Dt,
                                                 const float* __restrict__ Bg,
                                                 ushort_t* __restrict__ St) {
    const int chain = blockIdx.x >> 2;
    const int jq = (blockIdx.x & 3) * 16;
    const int tid = threadIdx.x;
    const int jj = jq + (tid >> 4);
    const int ii = (tid & 15) * 4;

    float4 S = make_float4(0.f, 0.f, 0.f, 0.f);
    for (int c = 0; c < NC; ++c) {
        const size_t base = (((size_t)chain * NC + c) * DHEAD + jj) * DHEAD + ii;
        ushort4 o;
        o.x = f2bf(S.x); o.y = f2bf(S.y); o.z = f2bf(S.z); o.w = f2bf(S.w);
        *(ushort4*)&St[base] = o;                 // state BEFORE chunk c
        const float eB = __expf(Bg[chain * NC + c]);
        const float4 D = *(const float4*)&Dt[base];
        S.x = eB * S.x + D.x;
        S.y = eB * S.y + D.y;
        S.z = eB * S.z + D.z;
        S.w = eB * S.w + D.w;
    }
}

// ---------------------------------------------------------------------------
// Phase 3: per (chain, chunk) tile:
//   A    = Q @ St            (inter-chunk term, row-scaled by e^{b_t} later)
//   P    = Q @ K^T ;  P~ = P * e^{b_t - b_tau} * (tau<=t)
//   Y    = diag(e^{b_t}) A + P~ @ V        -> yb (bf16)
// P~ round-trips LDS (C-layout -> A-layout); rows are wave-private.
// ---------------------------------------------------------------------------
__global__ __launch_bounds__(256) void p3_kernel(const ushort_t* __restrict__ qb,
                                                 const ushort_t* __restrict__ kb,
                                                 const ushort_t* __restrict__ vb,
                                                 const ushort_t* __restrict__ St,
                                                 const float* __restrict__ gate,
                                                 ushort_t* __restrict__ yb) {
    const int tile = blockIdx.x;
    const int chain = tile >> 5;
    const int c = tile & 31;
    const int b = chain >> 4;
    const int h = chain & 15;
    const int tid = threadIdx.x;
    const int w = tid >> 6;
    const int l = tid & 63;

    __shared__ ushort_t Qs[CT * SP];
    __shared__ ushort_t Ks[CT * SP];
    __shared__ ushort_t Vs[CT * SP];
    __shared__ ushort_t Ss[CT * SP];
    __shared__ ushort_t Ps[CT * SP];
    __shared__ float bs[CT];

    // stage Q,K,V chunk + St tile
    {
        const int row = tid >> 2;
        const int seg = (tid & 3) * 16;
        const size_t grow = ((size_t)(b * SEQ + c * CT + row)) * DMODEL + h * DHEAD + seg;
        float4 q0 = *(const float4*)&qb[grow];
        float4 q1 = *(const float4*)&qb[grow + 8];
        float4 k0 = *(const float4*)&kb[grow + 0];
        float4 k1 = *(const float4*)&kb[grow + 8];
        float4 v0 = *(const float4*)&vb[grow];
        float4 v1 = *(const float4*)&vb[grow + 8];
        const size_t srow = (((size_t)chain * NC + c) * DHEAD + row) * DHEAD + seg;
        float4 s0 = *(const float4*)&St[srow];
        float4 s1 = *(const float4*)&St[srow + 8];
        *(float4*)&Qs[row * SP + seg]     = q0;
        *(float4*)&Qs[row * SP + seg + 8] = q1;
        *(float4*)&Ks[row * SP + seg]     = k0;
        *(float4*)&Ks[row * SP + seg + 8] = k1;
        *(float4*)&Vs[row * SP + seg]     = v0;
        *(float4*)&Vs[row * SP + seg + 8] = v1;
        *(float4*)&Ss[row * SP + seg]     = s0;
        *(float4*)&Ss[row * SP + seg + 8] = s1;
    }
    if (tid < 64) {
        float g = gate[((size_t)(b * SEQ + c * CT + tid)) * NHEADS + h];
        float lg = __logf(g);
#pragma unroll
        for (int d = 1; d < 64; d <<= 1) {
            float n = __shfl_up(lg, d, 64);
            if (l >= d) lg += n;
        }
        bs[tid] = lg;
    }
    __syncthreads();

    const int fr = l & 15;
    const int fq = (l >> 4) * 8;
    const int tw = w * 16;

    bf16x8 qa[2];
#pragma unroll
    for (int kc = 0; kc < 2; ++kc)
        qa[kc] = *(const bf16x8*)&Qs[(tw + fr) * SP + kc * 32 + fq];

    f32x4 accA[4], accP[4];
#pragma unroll
    for (int nt = 0; nt < 4; ++nt)
#pragma unroll
        for (int r = 0; r < 4; ++r) { accA[nt][r] = 0.f; accP[nt][r] = 0.f; }

#pragma unroll
    for (int kc = 0; kc < 2; ++kc)
#pragma unroll
        for (int nt = 0; nt < 4; ++nt) {
            bf16x8 sb = *(const bf16x8*)&Ss[(nt * 16 + fr) * SP + kc * 32 + fq];
            accA[nt] = __builtin_amdgcn_mfma_f32_16x16x32_bf16(qa[kc], sb, accA[nt], 0, 0, 0);
            bf16x8 kf = *(const bf16x8*)&Ks[(nt * 16 + fr) * SP + kc * 32 + fq];
            accP[nt] = __builtin_amdgcn_mfma_f32_16x16x32_bf16(qa[kc], kf, accP[nt], 0, 0, 0);
        }

    // gated, masked P~ -> LDS (bf16)
    const int er = (l >> 4) * 4;
    int trow[4];
    float bt[4];
#pragma unroll
    for (int r = 0; r < 4; ++r) { trow[r] = tw + er + r; bt[r] = bs[trow[r]]; }
#pragma unroll
    for (int nt = 0; nt < 4; ++nt) {
        const int tau = nt * 16 + fr;
        const float btau = bs[tau];
#pragma unroll
        for (int r = 0; r < 4; ++r) {
            float f = (tau <= trow[r]) ? __expf(bt[r] - btau) : 0.f;
            Ps[trow[r] * SP + tau] = f2bf(accP[nt][r] * f);
        }
    }
    __syncthreads();   // safety: order P~ writes before reads (rows are wave-private)

    // Y = diag(e^{b_t}) A + P~ @ V
    f32x4 accY[4];
#pragma unroll
    for (int r = 0; r < 4; ++r) {
        const float eb = __expf(bt[r]);
#pragma unroll
        for (int nt = 0; nt < 4; ++nt) accY[nt][r] = accA[nt][r] * eb;
    }
#pragma unroll
    for (int kc = 0; kc < 2; ++kc) {
        bf16x8 pa = *(const bf16x8*)&Ps[(tw + fr) * SP + kc * 32 + fq];
#pragma unroll
        for (int nt = 0; nt < 4; ++nt) {
            bf16x8 vf;
#pragma unroll
            for (int m = 0; m < 8; ++m)
                vf[m] = (short)Vs[(kc * 32 + fq + m) * SP + nt * 16 + fr];
            accY[nt] = __builtin_amdgcn_mfma_f32_16x16x32_bf16(pa, vf, accY[nt], 0, 0, 0);
        }
    }

    const size_t ybase = ((size_t)(b * SEQ + c * CT)) * DMODEL + h * DHEAD;
#pragma unroll
    for (int nt = 0; nt < 4; ++nt)
#pragma unroll
        for (int r = 0; r < 4; ++r)
            yb[ybase + (size_t)trow[r] * DMODEL + nt * 16 + fr] = f2bf(accY[nt][r]);
}

// ---------------------------------------------------------------------------
// Host launch
// ---------------------------------------------------------------------------
extern "C" void kernel_launch(void* const* d_in, const int* in_sizes, int n_in,
                              void* d_out, int out_size, void* d_ws, size_t ws_size,
                              hipStream_t stream) {
    const float* x  = (const float*)d_in[0];
    const float* Wq = (const float*)d_in[1];
    const float* Wk = (const float*)d_in[2];
    const float* Wv = (const float*)d_in[3];
    const float* Wo = (const float*)d_in[4];
    const float* Wg = (const float*)d_in[5];
    const float* bg = (const float*)d_in[6];
    float* out = (float*)d_out;

    const size_t elems = (size_t)MTOK * DMODEL;     // 8,388,608
    const size_t welems = (size_t)DMODEL * DMODEL;  // 1,048,576
    const size_t stelems = (size_t)NCHAIN * NC * DHEAD * DHEAD;   // 8,388,608

    // layout (ushort units unless noted):
    // [xb][kb][vb][yb][wqb][wkb][wvb][wob] [gate f32][St][Bg f32][Dt f32 / qb alias]
    ushort_t* xb  = (ushort_t*)d_ws;
    ushort_t* kb  = xb + elems;
    ushort_t* vb  = kb + elems;
    ushort_t* yb  = vb + elems;
    ushort_t* wqb = yb + elems;
    ushort_t* wkb = wqb + welems;
    ushort_t* wvb = wkb + welems;
    ushort_t* wob = wvb + welems;
    float* gate   = (float*)(wob + welems);
    ushort_t* St  = (ushort_t*)(gate + (size_t)MTOK * NHEADS);
    float* Bg     = (float*)(St + stelems);
    float* Dt     = Bg + (size_t)NCHAIN * NC;
    ushort_t* qb  = (ushort_t*)Dt;    // alias: Dt dead after phase 2; q-proj runs after

    const size_t need = (size_t)((char*)(Dt + stelems) - (char*)d_ws);  // ~126 MB
    if (ws_size < need) return;

    // converts
    cvt_f32_bf16<<<dim3((int)(elems / 4 / 256)), dim3(256), 0, stream>>>(x, xb, (int)(elems / 4));
    cvt_f32_bf16<<<dim3((int)(welems / 4 / 256)), dim3(256), 0, stream>>>(Wq, wqb, (int)(welems / 4));
    cvt_f32_bf16<<<dim3((int)(welems / 4 / 256)), dim3(256), 0, stream>>>(Wk, wkb, (int)(welems / 4));
    cvt_f32_bf16<<<dim3((int)(welems / 4 / 256)), dim3(256), 0, stream>>>(Wv, wvb, (int)(welems / 4));
    cvt_f32_bf16<<<dim3((int)(welems / 4 / 256)), dim3(256), 0, stream>>>(Wo, wob, (int)(welems / 4));

    dim3 gridG(DMODEL / GT, MTOK / GT);   // (8, 64)
    dim3 blockG(256);

    // K, V projections (bf16 out) and gate
    gemm_bf16<<<gridG, blockG, 0, stream>>>(xb, wkb, nullptr, kb, MTOK, DMODEL, DMODEL, 1, 1.0f);
    gemm_bf16<<<gridG, blockG, 0, stream>>>(xb, wvb, nullptr, vb, MTOK, DMODEL, DMODEL, 2, 1.0f);
    gate_kernel<<<dim3(MTOK), dim3(256), 0, stream>>>(x, Wg, bg, gate);

    // chunked linear-attention scan
    p1_kernel<<<dim3(NCHAIN * NC), dim3(256), 0, stream>>>(kb, vb, gate, Dt, Bg);
    p2_kernel<<<dim3(NCHAIN * 4), dim3(256), 0, stream>>>(Dt, Bg, St);

    // Q projection AFTER phase 2 (qb aliases Dt)
    gemm_bf16<<<gridG, blockG, 0, stream>>>(xb, wqb, nullptr, qb, MTOK, DMODEL, DMODEL, 1, SCALE_Q);

    p3_kernel<<<dim3(NCHAIN * NC), dim3(256), 0, stream>>>(qb, kb, vb, St, gate, yb);

    // output projection (fp32 out)
    gemm_bf16<<<gridG, blockG, 0, stream>>>(yb, wob, out, nullptr, MTOK, DMODEL, DMODEL, 0, 1.0f);
}

// Round 6
// 286.627 us; speedup vs baseline: 7.9339x; 1.1129x over previous
//
#include <hip/hip_runtime.h>
#include <hip/hip_bf16.h>
#include <math.h>

// Problem constants
#define BATCH 4
#define SEQ 2048
#define DMODEL 1024
#define NHEADS 16
#define DHEAD 64
#define MTOK (BATCH * SEQ)          // 8192 tokens
#define SCALE_Q 0.125f              // 1/sqrt(64)
#define NCHAIN (BATCH * NHEADS)     // 64
#define CT 64                       // chunk length (timesteps)
#define NC (SEQ / CT)               // 32 chunks per chain
#define SP 72                       // padded LDS row stride (ushorts); 144B
#define QKVS 3072                   // row stride of fused qkv buffer

typedef unsigned short ushort_t;
typedef __attribute__((ext_vector_type(8))) short bf16x8;   // 8 bf16 in 4 VGPRs
typedef __attribute__((ext_vector_type(4))) float f32x4;

__device__ __forceinline__ float bf2f(unsigned short u) {
    return __uint_as_float(((unsigned)u) << 16);
}
__device__ __forceinline__ unsigned short f2bf(float f) {
    unsigned u = __float_as_uint(f);
    return (unsigned short)((u + 0x7fffu + ((u >> 16) & 1u)) >> 16);  // RNE
}

// ---------------------------------------------------------------------------
// fp32 -> bf16 convert (x)
// ---------------------------------------------------------------------------
__global__ __launch_bounds__(256) void cvt_f32_bf16(const float* __restrict__ in,
                                                    ushort_t* __restrict__ out, int n4) {
    int i = blockIdx.x * 256 + threadIdx.x;
    if (i < n4) {
        float4 v = ((const float4*)in)[i];
        ushort4 o;
        o.x = f2bf(v.x); o.y = f2bf(v.y); o.z = f2bf(v.z); o.w = f2bf(v.w);
        ((ushort4*)out)[i] = o;
    }
}

// ---------------------------------------------------------------------------
// Weight concat + convert: dest rows [0,1024)=Wq, [1024,2048)=Wk,
// [2048,3072)=Wv, [3072,4096)=Wo.  4096x1024 fp32 -> bf16.
// ---------------------------------------------------------------------------
__global__ __launch_bounds__(256) void cvt_weights(const float* __restrict__ Wq,
                                                   const float* __restrict__ Wk,
                                                   const float* __restrict__ Wv,
                                                   const float* __restrict__ Wo,
                                                   ushort_t* __restrict__ dst) {
    int i = blockIdx.x * 256 + threadIdx.x;           // float4 index, < 1048576
    const int row = i >> 8;                            // / (1024/4)
    const int c4 = i & 255;
    const float* src;
    if (row < 1024)      src = Wq + (size_t)row * DMODEL;
    else if (row < 2048) src = Wk + (size_t)(row - 1024) * DMODEL;
    else if (row < 3072) src = Wv + (size_t)(row - 2048) * DMODEL;
    else                 src = Wo + (size_t)(row - 3072) * DMODEL;
    float4 v = ((const float4*)src)[c4];
    ushort4 o;
    o.x = f2bf(v.x); o.y = f2bf(v.y); o.z = f2bf(v.z); o.w = f2bf(v.w);
    ((ushort4*)(dst + (size_t)row * DMODEL))[c4] = o;
}

// ---------------------------------------------------------------------------
// bf16 MFMA GEMM (m97 structure): C[M,N] = ep( A[M,K] @ B[N,K]^T )
// mode 0: identity -> fp32 Cf
// mode 3: fused QKV epilogue -> bf16 Cb: cols [0,1024) phi(acc*SCALE_Q),
//         [1024,2048) phi(acc), [2048,3072) identity.  (128-tiles never
//         straddle 1024 boundaries, so flags are block-uniform.)
// ---------------------------------------------------------------------------
#define GT 128
#define GBK 32

__global__ __launch_bounds__(256) void gemm_bf16(const ushort_t* __restrict__ A,
                                                 const ushort_t* __restrict__ B,
                                                 float* __restrict__ Cf,
                                                 ushort_t* __restrict__ Cb,
                                                 int M, int N, int K,
                                                 int mode) {
    __shared__ ushort_t As[GT * GBK];   // [row][k] k-contiguous, no pad (DMA constraint)
    __shared__ ushort_t Bs[GT * GBK];

    const int tid = threadIdx.x;
    const int w = tid >> 6;
    const int l = tid & 63;
    const int m0 = blockIdx.y * GT;
    const int n0 = blockIdx.x * GT;
    const int wm = (w >> 1) * 64;
    const int wn = (w & 1) * 64;

    const int srow = l >> 2;
    const int schunk = (l & 3) * 8;

    f32x4 acc[4][4];
#pragma unroll
    for (int i = 0; i < 4; ++i)
#pragma unroll
        for (int j = 0; j < 4; ++j)
#pragma unroll
            for (int r = 0; r < 4; ++r) acc[i][j][r] = 0.f;

    const int fr = l & 15;
    const int fq = (l >> 4) * 8;

    for (int k0 = 0; k0 < K; k0 += GBK) {
        __syncthreads();
#pragma unroll
        for (int i = 0; i < 2; ++i) {
            const int s = w * 2 + i;
            const ushort_t* ga = A + (size_t)(m0 + s * 16 + srow) * K + k0 + schunk;
            const ushort_t* gb = B + (size_t)(n0 + s * 16 + srow) * K + k0 + schunk;
            __builtin_amdgcn_global_load_lds(
                (const __attribute__((address_space(1))) unsigned int*)(const void*)ga,
                (__attribute__((address_space(3))) unsigned int*)(void*)&As[s * 16 * GBK],
                16, 0, 0);
            __builtin_amdgcn_global_load_lds(
                (const __attribute__((address_space(1))) unsigned int*)(const void*)gb,
                (__attribute__((address_space(3))) unsigned int*)(void*)&Bs[s * 16 * GBK],
                16, 0, 0);
        }
        __syncthreads();

        bf16x8 af[4], bfr[4];
#pragma unroll
        for (int ti = 0; ti < 4; ++ti)
            af[ti] = *(const bf16x8*)&As[(wm + ti * 16 + fr) * GBK + fq];
#pragma unroll
        for (int tj = 0; tj < 4; ++tj)
            bfr[tj] = *(const bf16x8*)&Bs[(wn + tj * 16 + fr) * GBK + fq];
#pragma unroll
        for (int ti = 0; ti < 4; ++ti)
#pragma unroll
            for (int tj = 0; tj < 4; ++tj)
                acc[ti][tj] = __builtin_amdgcn_mfma_f32_16x16x32_bf16(
                    af[ti], bfr[tj], acc[ti][tj], 0, 0, 0);
    }

    // block-uniform epilogue flags
    float escale = 1.0f;
    bool do_phi = false;
    if (mode == 3) {
        do_phi = (n0 < 2048);
        escale = (n0 < 1024) ? SCALE_Q : 1.0f;
    }

    const int er = (l >> 4) * 4;
    const int ec = l & 15;
#pragma unroll
    for (int ti = 0; ti < 4; ++ti)
#pragma unroll
        for (int tj = 0; tj < 4; ++tj)
#pragma unroll
            for (int r = 0; r < 4; ++r) {
                const int row = m0 + wm + ti * 16 + er + r;
                const int col = n0 + wn + tj * 16 + ec;
                float val = acc[ti][tj][r];
                if (mode == 0) {
                    Cf[(size_t)row * N + col] = val;
                } else {
                    val *= escale;
                    if (do_phi) val = (val > 0.f) ? (val + 1.f) : __expf(val);  // elu+1
                    Cb[(size_t)row * N + col] = f2bf(val);
                }
            }
}

// ---------------------------------------------------------------------------
// Gate: gate[m][h] = sigmoid( sum_k x[m][k] * Wg[h][k] + bg[h] )   (fp32)
// ---------------------------------------------------------------------------
__global__ __launch_bounds__(256) void gate_kernel(const float* __restrict__ x,
                                                   const float* __restrict__ Wg,
                                                   const float* __restrict__ bg,
                                                   float* __restrict__ gate) {
    const int m = blockIdx.x;
    const int tid = threadIdx.x;
    const int h = tid >> 4;
    const int r = tid & 15;

    const float* xr = x + (size_t)m * DMODEL;
    const float* wr = Wg + (size_t)h * DMODEL;

    float p = 0.f;
#pragma unroll
    for (int i = 0; i < 16; ++i) {
        const int k = (r << 2) + (i << 6);
        float4 xv = *(const float4*)&xr[k];
        float4 wv = *(const float4*)&wr[k];
        p += xv.x * wv.x + xv.y * wv.y + xv.z * wv.z + xv.w * wv.w;
    }
    p += __shfl_xor(p, 8, 64);
    p += __shfl_xor(p, 4, 64);
    p += __shfl_xor(p, 2, 64);
    p += __shfl_xor(p, 1, 64);
    if (r == 0) {
        float vv = p + bg[h];
        gate[(size_t)m * NHEADS + h] = 1.f / (1.f + __expf(-vv));
    }
}

// ---------------------------------------------------------------------------
// Phase 1: per (chain, chunk) tile, decay-weighted KV outer-product sum
//   Dt[j][i] = sum_tau e^{b63 - b_tau} * v[tau][j] * k[tau][i]   (fp32)
// ---------------------------------------------------------------------------
__global__ __launch_bounds__(256) void p1_kernel(const ushort_t* __restrict__ qkv,
                                                 const float* __restrict__ gate,
                                                 float* __restrict__ Dt,
                                                 float* __restrict__ Bg) {
    const int tile = blockIdx.x;          // 0..2047
    const int chain = tile >> 5;
    const int c = tile & 31;
    const int b = chain >> 4;
    const int h = chain & 15;
    const int tid = threadIdx.x;
    const int w = tid >> 6;
    const int l = tid & 63;

    __shared__ ushort_t Ks[CT * SP];
    __shared__ ushort_t Vs[CT * SP];
    __shared__ float bs[CT];

    {
        const int row = tid >> 2;
        const int seg = (tid & 3) * 16;
        const size_t grow = ((size_t)(b * SEQ + c * CT + row)) * QKVS + h * DHEAD + seg;
        float4 a0 = *(const float4*)&qkv[grow + 1024];      // k
        float4 a1 = *(const float4*)&qkv[grow + 1024 + 8];
        float4 b0 = *(const float4*)&qkv[grow + 2048];      // v
        float4 b1 = *(const float4*)&qkv[grow + 2048 + 8];
        *(float4*)&Ks[row * SP + seg]     = a0;
        *(float4*)&Ks[row * SP + seg + 8] = a1;
        *(float4*)&Vs[row * SP + seg]     = b0;
        *(float4*)&Vs[row * SP + seg + 8] = b1;
    }
    if (tid < 64) {
        float g = gate[((size_t)(b * SEQ + c * CT + tid)) * NHEADS + h];
        float lg = __logf(g);
#pragma unroll
        for (int d = 1; d < 64; d <<= 1) {
            float n = __shfl_up(lg, d, 64);
            if (l >= d) lg += n;
        }
        bs[tid] = lg;
        if (tid == 63) Bg[tile] = lg;
    }
    __syncthreads();

    const float B = bs[63];
    const int fr = l & 15;
    const int fq = (l >> 4) * 8;
    const int jw = w * 16;

    f32x4 accD[4];
#pragma unroll
    for (int nt = 0; nt < 4; ++nt)
#pragma unroll
        for (int r = 0; r < 4; ++r) accD[nt][r] = 0.f;

#pragma unroll
    for (int kc = 0; kc < 2; ++kc) {
        float ef[8];
#pragma unroll
        for (int m = 0; m < 8; ++m) ef[m] = __expf(B - bs[kc * 32 + fq + m]);
        bf16x8 va;
#pragma unroll
        for (int m = 0; m < 8; ++m)
            va[m] = (short)Vs[(kc * 32 + fq + m) * SP + jw + fr];
#pragma unroll
        for (int nt = 0; nt < 4; ++nt) {
            bf16x8 kf;
#pragma unroll
            for (int m = 0; m < 8; ++m)
                kf[m] = (short)f2bf(ef[m] * bf2f(Ks[(kc * 32 + fq + m) * SP + nt * 16 + fr]));
            accD[nt] = __builtin_amdgcn_mfma_f32_16x16x32_bf16(va, kf, accD[nt], 0, 0, 0);
        }
    }

    const int er = (l >> 4) * 4;
    const size_t dbase = (size_t)tile * (DHEAD * DHEAD);
#pragma unroll
    for (int nt = 0; nt < 4; ++nt)
#pragma unroll
        for (int r = 0; r < 4; ++r) {
            const int j = jw + er + r;
            const int i = nt * 16 + fr;
            Dt[dbase + j * DHEAD + i] = accD[nt][r];
        }
}

// ---------------------------------------------------------------------------
// Phase 2: sequential over 32 chunks; St[c] = state BEFORE chunk c (bf16,[j][i])
// ---------------------------------------------------------------------------
__global__ __launch_bounds__(256) void p2_kernel(const float* __restrict__ Dt,
                                                 const float* __restrict__ Bg,
                                                 ushort_t* __restrict__ St) {
    const int chain = blockIdx.x >> 2;
    const int jq = (blockIdx.x & 3) * 16;
    const int tid = threadIdx.x;
    const int jj = jq + (tid >> 4);
    const int ii = (tid & 15) * 4;

    float4 S = make_float4(0.f, 0.f, 0.f, 0.f);
    for (int c = 0; c < NC; ++c) {
        const size_t base = (((size_t)chain * NC + c) * DHEAD + jj) * DHEAD + ii;
        ushort4 o;
        o.x = f2bf(S.x); o.y = f2bf(S.y); o.z = f2bf(S.z); o.w = f2bf(S.w);
        *(ushort4*)&St[base] = o;
        const float eB = __expf(Bg[chain * NC + c]);
        const float4 D = *(const float4*)&Dt[base];
        S.x = eB * S.x + D.x;
        S.y = eB * S.y + D.y;
        S.z = eB * S.z + D.z;
        S.w = eB * S.w + D.w;
    }
}

// ---------------------------------------------------------------------------
// Phase 3: Y = diag(e^{b_t}) (Q@St) + (QK^T ⊙ decay ⊙ mask) @ V   -> yb bf16
// ---------------------------------------------------------------------------
__global__ __launch_bounds__(256) void p3_kernel(const ushort_t* __restrict__ qkv,
                                                 const ushort_t* __restrict__ St,
                                                 const float* __restrict__ gate,
                                                 ushort_t* __restrict__ yb) {
    const int tile = blockIdx.x;
    const int chain = tile >> 5;
    const int c = tile & 31;
    const int b = chain >> 4;
    const int h = chain & 15;
    const int tid = threadIdx.x;
    const int w = tid >> 6;
    const int l = tid & 63;

    __shared__ ushort_t Qs[CT * SP];
    __shared__ ushort_t Ks[CT * SP];
    __shared__ ushort_t Vs[CT * SP];
    __shared__ ushort_t Ss[CT * SP];
    __shared__ ushort_t Ps[CT * SP];
    __shared__ float bs[CT];

    {
        const int row = tid >> 2;
        const int seg = (tid & 3) * 16;
        const size_t grow = ((size_t)(b * SEQ + c * CT + row)) * QKVS + h * DHEAD + seg;
        float4 q0 = *(const float4*)&qkv[grow];
        float4 q1 = *(const float4*)&qkv[grow + 8];
        float4 k0 = *(const float4*)&qkv[grow + 1024];
        float4 k1 = *(const float4*)&qkv[grow + 1024 + 8];
        float4 v0 = *(const float4*)&qkv[grow + 2048];
        float4 v1 = *(const float4*)&qkv[grow + 2048 + 8];
        const size_t srow = (((size_t)chain * NC + c) * DHEAD + row) * DHEAD + seg;
        float4 s0 = *(const float4*)&St[srow];
        float4 s1 = *(const float4*)&St[srow + 8];
        *(float4*)&Qs[row * SP + seg]     = q0;
        *(float4*)&Qs[row * SP + seg + 8] = q1;
        *(float4*)&Ks[row * SP + seg]     = k0;
        *(float4*)&Ks[row * SP + seg + 8] = k1;
        *(float4*)&Vs[row * SP + seg]     = v0;
        *(float4*)&Vs[row * SP + seg + 8] = v1;
        *(float4*)&Ss[row * SP + seg]     = s0;
        *(float4*)&Ss[row * SP + seg + 8] = s1;
    }
    if (tid < 64) {
        float g = gate[((size_t)(b * SEQ + c * CT + tid)) * NHEADS + h];
        float lg = __logf(g);
#pragma unroll
        for (int d = 1; d < 64; d <<= 1) {
            float n = __shfl_up(lg, d, 64);
            if (l >= d) lg += n;
        }
        bs[tid] = lg;
    }
    __syncthreads();

    const int fr = l & 15;
    const int fq = (l >> 4) * 8;
    const int tw = w * 16;

    bf16x8 qa[2];
#pragma unroll
    for (int kc = 0; kc < 2; ++kc)
        qa[kc] = *(const bf16x8*)&Qs[(tw + fr) * SP + kc * 32 + fq];

    f32x4 accA[4], accP[4];
#pragma unroll
    for (int nt = 0; nt < 4; ++nt)
#pragma unroll
        for (int r = 0; r < 4; ++r) { accA[nt][r] = 0.f; accP[nt][r] = 0.f; }

#pragma unroll
    for (int kc = 0; kc < 2; ++kc)
#pragma unroll
        for (int nt = 0; nt < 4; ++nt) {
            bf16x8 sb = *(const bf16x8*)&Ss[(nt * 16 + fr) * SP + kc * 32 + fq];
            accA[nt] = __builtin_amdgcn_mfma_f32_16x16x32_bf16(qa[kc], sb, accA[nt], 0, 0, 0);
            bf16x8 kf = *(const bf16x8*)&Ks[(nt * 16 + fr) * SP + kc * 32 + fq];
            accP[nt] = __builtin_amdgcn_mfma_f32_16x16x32_bf16(qa[kc], kf, accP[nt], 0, 0, 0);
        }

    const int er = (l >> 4) * 4;
    int trow[4];
    float bt[4];
#pragma unroll
    for (int r = 0; r < 4; ++r) { trow[r] = tw + er + r; bt[r] = bs[trow[r]]; }
#pragma unroll
    for (int nt = 0; nt < 4; ++nt) {
        const int tau = nt * 16 + fr;
        const float btau = bs[tau];
#pragma unroll
        for (int r = 0; r < 4; ++r) {
            float f = (tau <= trow[r]) ? __expf(bt[r] - btau) : 0.f;
            Ps[trow[r] * SP + tau] = f2bf(accP[nt][r] * f);
        }
    }
    __syncthreads();

    f32x4 accY[4];
#pragma unroll
    for (int r = 0; r < 4; ++r) {
        const float eb = __expf(bt[r]);
#pragma unroll
        for (int nt = 0; nt < 4; ++nt) accY[nt][r] = accA[nt][r] * eb;
    }
#pragma unroll
    for (int kc = 0; kc < 2; ++kc) {
        bf16x8 pa = *(const bf16x8*)&Ps[(tw + fr) * SP + kc * 32 + fq];
#pragma unroll
        for (int nt = 0; nt < 4; ++nt) {
            bf16x8 vf;
#pragma unroll
            for (int m = 0; m < 8; ++m)
                vf[m] = (short)Vs[(kc * 32 + fq + m) * SP + nt * 16 + fr];
            accY[nt] = __builtin_amdgcn_mfma_f32_16x16x32_bf16(pa, vf, accY[nt], 0, 0, 0);
        }
    }

    const size_t ybase = ((size_t)(b * SEQ + c * CT)) * DMODEL + h * DHEAD;
#pragma unroll
    for (int nt = 0; nt < 4; ++nt)
#pragma unroll
        for (int r = 0; r < 4; ++r)
            yb[ybase + (size_t)trow[r] * DMODEL + nt * 16 + fr] = f2bf(accY[nt][r]);
}

// ---------------------------------------------------------------------------
// Host launch
// ---------------------------------------------------------------------------
extern "C" void kernel_launch(void* const* d_in, const int* in_sizes, int n_in,
                              void* d_out, int out_size, void* d_ws, size_t ws_size,
                              hipStream_t stream) {
    const float* x  = (const float*)d_in[0];
    const float* Wq = (const float*)d_in[1];
    const float* Wk = (const float*)d_in[2];
    const float* Wv = (const float*)d_in[3];
    const float* Wo = (const float*)d_in[4];
    const float* Wg = (const float*)d_in[5];
    const float* bg = (const float*)d_in[6];
    float* out = (float*)d_out;

    const size_t elems = (size_t)MTOK * DMODEL;     // 8,388,608
    const size_t welems = (size_t)DMODEL * DMODEL;  // 1,048,576
    const size_t stelems = (size_t)NCHAIN * NC * DHEAD * DHEAD;   // 8,388,608

    // layout: [xb][qkv][yb][wcat(4W)] [gate f32][St][Bg f32][Dt f32]
    ushort_t* xb   = (ushort_t*)d_ws;
    ushort_t* qkv  = xb + elems;                    // [8192][3072]
    ushort_t* yb   = qkv + (size_t)MTOK * QKVS;
    ushort_t* wcat = yb + elems;                    // rows: Wq,Wk,Wv,Wo
    float* gate    = (float*)(wcat + 4 * welems);
    ushort_t* St   = (ushort_t*)(gate + (size_t)MTOK * NHEADS);
    float* Bg      = (float*)(St + stelems);
    float* Dt      = Bg + (size_t)NCHAIN * NC;

    const size_t need = (size_t)((char*)(Dt + stelems) - (char*)d_ws);  // ~144 MB
    if (ws_size < need) return;

    // converts (2 launches)
    cvt_f32_bf16<<<dim3((int)(elems / 4 / 256)), dim3(256), 0, stream>>>(x, xb, (int)(elems / 4));
    cvt_weights<<<dim3((int)(4 * welems / 4 / 256)), dim3(256), 0, stream>>>(Wq, Wk, Wv, Wo, wcat);

    // fused QKV projection: N=3072, epilogue per column range
    gemm_bf16<<<dim3(QKVS / GT, MTOK / GT), dim3(256), 0, stream>>>(
        xb, wcat, nullptr, qkv, MTOK, QKVS, DMODEL, 3);

    gate_kernel<<<dim3(MTOK), dim3(256), 0, stream>>>(x, Wg, bg, gate);

    // chunked linear-attention scan
    p1_kernel<<<dim3(NCHAIN * NC), dim3(256), 0, stream>>>(qkv, gate, Dt, Bg);
    p2_kernel<<<dim3(NCHAIN * 4), dim3(256), 0, stream>>>(Dt, Bg, St);
    p3_kernel<<<dim3(NCHAIN * NC), dim3(256), 0, stream>>>(qkv, St, gate, yb);

    // output projection (fp32 out)
    gemm_bf16<<<dim3(DMODEL / GT, MTOK / GT), dim3(256), 0, stream>>>(
        yb, wcat + 3 * welems, out, nullptr, MTOK, DMODEL, DMODEL, 0);
}

// Round 7
// 268.229 us; speedup vs baseline: 8.4780x; 1.0686x over previous
//
#include <hip/hip_runtime.h>
#include <hip/hip_bf16.h>
#include <math.h>

// Problem constants
#define BATCH 4
#define SEQ 2048
#define DMODEL 1024
#define NHEADS 16
#define DHEAD 64
#define MTOK (BATCH * SEQ)          // 8192 tokens
#define SCALE_Q 0.125f              // 1/sqrt(64)
#define NCHAIN (BATCH * NHEADS)     // 64
#define CT 64                       // chunk length (timesteps)
#define NC (SEQ / CT)               // 32 chunks per chain
#define SP 72                       // padded LDS row stride (ushorts); 144B
#define QKVS 3072                   // row stride of fused qkv buffer

typedef unsigned short ushort_t;
typedef __attribute__((ext_vector_type(8))) short bf16x8;   // 8 bf16 in 4 VGPRs
typedef __attribute__((ext_vector_type(4))) float f32x4;

__device__ __forceinline__ float bf2f(unsigned short u) {
    return __uint_as_float(((unsigned)u) << 16);
}
__device__ __forceinline__ unsigned short f2bf(float f) {
    unsigned u = __float_as_uint(f);
    return (unsigned short)((u + 0x7fffu + ((u >> 16) & 1u)) >> 16);  // RNE
}

// ---------------------------------------------------------------------------
// fp32 -> bf16 convert (x)
// ---------------------------------------------------------------------------
__global__ __launch_bounds__(256) void cvt_f32_bf16(const float* __restrict__ in,
                                                    ushort_t* __restrict__ out, int n4) {
    int i = blockIdx.x * 256 + threadIdx.x;
    if (i < n4) {
        float4 v = ((const float4*)in)[i];
        ushort4 o;
        o.x = f2bf(v.x); o.y = f2bf(v.y); o.z = f2bf(v.z); o.w = f2bf(v.w);
        ((ushort4*)out)[i] = o;
    }
}

// ---------------------------------------------------------------------------
// Weight concat + convert: rows [0,1024)=Wq, [1024,2048)=Wk, [2048,3072)=Wv,
// [3072,4096)=Wo.  4096x1024 fp32 -> bf16.
// ---------------------------------------------------------------------------
__global__ __launch_bounds__(256) void cvt_weights(const float* __restrict__ Wq,
                                                   const float* __restrict__ Wk,
                                                   const float* __restrict__ Wv,
                                                   const float* __restrict__ Wo,
                                                   ushort_t* __restrict__ dst) {
    int i = blockIdx.x * 256 + threadIdx.x;           // float4 index, < 1048576
    const int row = i >> 8;
    const int c4 = i & 255;
    const float* src;
    if (row < 1024)      src = Wq + (size_t)row * DMODEL;
    else if (row < 2048) src = Wk + (size_t)(row - 1024) * DMODEL;
    else if (row < 3072) src = Wv + (size_t)(row - 2048) * DMODEL;
    else                 src = Wo + (size_t)(row - 3072) * DMODEL;
    float4 v = ((const float4*)src)[c4];
    ushort4 o;
    o.x = f2bf(v.x); o.y = f2bf(v.y); o.z = f2bf(v.z); o.w = f2bf(v.w);
    ((ushort4*)(dst + (size_t)row * DMODEL))[c4] = o;
}

// ---------------------------------------------------------------------------
// bf16 MFMA GEMM: C[M,N] = ep( A[M,K] @ B[N,K]^T )
// 128x128 tile, BK=32, double-buffered LDS (1 barrier/iter), XOR bank swizzle.
// LDS layout: slot s (16B) at row r holds global k-chunk s ^ ((r>>1)&3) —
// DMA-compatible (pure lane permutation within each 1KB segment); fragment
// ds_read_b128 becomes 2-way banked (free, m136) instead of 8-way.
// mode 0: identity -> fp32 Cf
// mode 3: fused QKV epilogue -> bf16 Cb: cols [0,1024) phi(acc*SCALE_Q),
//         [1024,2048) phi(acc), [2048,3072) identity.
// ---------------------------------------------------------------------------
#define GT 128
#define GBK 32

__global__ __launch_bounds__(256) void gemm_bf16(const ushort_t* __restrict__ A,
                                                 const ushort_t* __restrict__ B,
                                                 float* __restrict__ Cf,
                                                 ushort_t* __restrict__ Cb,
                                                 int M, int N, int K,
                                                 int mode) {
    __shared__ ushort_t As[2][GT * GBK];   // 8 KB each buffer
    __shared__ ushort_t Bs[2][GT * GBK];

    const int tid = threadIdx.x;
    const int w = tid >> 6;
    const int l = tid & 63;
    const int m0 = blockIdx.y * GT;
    const int n0 = blockIdx.x * GT;
    const int wm = (w >> 1) * 64;
    const int wn = (w & 1) * 64;

    // staging: lane l -> LDS (row l>>2, slot l&3) of a 16-row segment;
    // swizzle => lane must fetch global chunk (l&3) ^ ((l>>3)&3)
    const int srow = l >> 2;
    const int schunk = ((l & 3) ^ ((l >> 3) & 3)) * 8;   // elements

    const ushort_t* aseg[2];
    const ushort_t* bseg[2];
#pragma unroll
    for (int i = 0; i < 2; ++i) {
        const int s = w * 2 + i;
        aseg[i] = A + (size_t)(m0 + s * 16 + srow) * K + schunk;
        bseg[i] = B + (size_t)(n0 + s * 16 + srow) * K + schunk;
    }

#define STAGE(buf, k0)                                                          \
    do {                                                                        \
        _Pragma("unroll")                                                       \
        for (int i_ = 0; i_ < 2; ++i_) {                                        \
            const int s_ = w * 2 + i_;                                          \
            __builtin_amdgcn_global_load_lds(                                   \
                (const __attribute__((address_space(1))) unsigned int*)(const void*)(aseg[i_] + (k0)), \
                (__attribute__((address_space(3))) unsigned int*)(void*)&As[buf][s_ * 16 * GBK], \
                16, 0, 0);                                                      \
            __builtin_amdgcn_global_load_lds(                                   \
                (const __attribute__((address_space(1))) unsigned int*)(const void*)(bseg[i_] + (k0)), \
                (__attribute__((address_space(3))) unsigned int*)(void*)&Bs[buf][s_ * 16 * GBK], \
                16, 0, 0);                                                      \
        }                                                                       \
    } while (0)

    f32x4 acc[4][4];
#pragma unroll
    for (int i = 0; i < 4; ++i)
#pragma unroll
        for (int j = 0; j < 4; ++j)
#pragma unroll
            for (int r = 0; r < 4; ++r) acc[i][j][r] = 0.f;

    const int fr = l & 15;
    // swizzled fragment slot: logical chunk c = l>>4 at row ...+fr
    const int fsw = (((l >> 4) ^ ((fr >> 1) & 3))) * 8;   // elements

    STAGE(0, 0);

    const int nit = K / GBK;
    for (int it = 0; it < nit; ++it) {
        __syncthreads();                  // buf[it&1] DMA landed; old reads done
        if (it + 1 < nit) STAGE((it + 1) & 1, (it + 1) * GBK);

        const ushort_t* __restrict__ as = As[it & 1];
        const ushort_t* __restrict__ bs = Bs[it & 1];

        bf16x8 af[4], bfr[4];
#pragma unroll
        for (int ti = 0; ti < 4; ++ti)
            af[ti] = *(const bf16x8*)&as[(wm + ti * 16 + fr) * GBK + fsw];
#pragma unroll
        for (int tj = 0; tj < 4; ++tj)
            bfr[tj] = *(const bf16x8*)&bs[(wn + tj * 16 + fr) * GBK + fsw];
#pragma unroll
        for (int ti = 0; ti < 4; ++ti)
#pragma unroll
            for (int tj = 0; tj < 4; ++tj)
                acc[ti][tj] = __builtin_amdgcn_mfma_f32_16x16x32_bf16(
                    af[ti], bfr[tj], acc[ti][tj], 0, 0, 0);
    }
#undef STAGE

    // block-uniform epilogue flags
    float escale = 1.0f;
    bool do_phi = false;
    if (mode == 3) {
        do_phi = (n0 < 2048);
        escale = (n0 < 1024) ? SCALE_Q : 1.0f;
    }

    const int er = (l >> 4) * 4;
    const int ec = l & 15;
#pragma unroll
    for (int ti = 0; ti < 4; ++ti)
#pragma unroll
        for (int tj = 0; tj < 4; ++tj)
#pragma unroll
            for (int r = 0; r < 4; ++r) {
                const int row = m0 + wm + ti * 16 + er + r;
                const int col = n0 + wn + tj * 16 + ec;
                float val = acc[ti][tj][r];
                if (mode == 0) {
                    Cf[(size_t)row * N + col] = val;
                } else {
                    val *= escale;
                    if (do_phi) val = (val > 0.f) ? (val + 1.f) : __expf(val);  // elu+1
                    Cb[(size_t)row * N + col] = f2bf(val);
                }
            }
}

// ---------------------------------------------------------------------------
// Gate: gate[m][h] = sigmoid( sum_k x[m][k] * Wg[h][k] + bg[h] )   (fp32)
// ---------------------------------------------------------------------------
__global__ __launch_bounds__(256) void gate_kernel(const float* __restrict__ x,
                                                   const float* __restrict__ Wg,
                                                   const float* __restrict__ bg,
                                                   float* __restrict__ gate) {
    const int m = blockIdx.x;
    const int tid = threadIdx.x;
    const int h = tid >> 4;
    const int r = tid & 15;

    const float* xr = x + (size_t)m * DMODEL;
    const float* wr = Wg + (size_t)h * DMODEL;

    float p = 0.f;
#pragma unroll
    for (int i = 0; i < 16; ++i) {
        const int k = (r << 2) + (i << 6);
        float4 xv = *(const float4*)&xr[k];
        float4 wv = *(const float4*)&wr[k];
        p += xv.x * wv.x + xv.y * wv.y + xv.z * wv.z + xv.w * wv.w;
    }
    p += __shfl_xor(p, 8, 64);
    p += __shfl_xor(p, 4, 64);
    p += __shfl_xor(p, 2, 64);
    p += __shfl_xor(p, 1, 64);
    if (r == 0) {
        float vv = p + bg[h];
        gate[(size_t)m * NHEADS + h] = 1.f / (1.f + __expf(-vv));
    }
}

// ---------------------------------------------------------------------------
// Phase 1: per (chain, chunk) tile, decay-weighted KV outer-product sum
//   Dt[j][i] = sum_tau e^{b63 - b_tau} * v[tau][j] * k[tau][i]   (fp32)
// ---------------------------------------------------------------------------
__global__ __launch_bounds__(256) void p1_kernel(const ushort_t* __restrict__ qkv,
                                                 const float* __restrict__ gate,
                                                 float* __restrict__ Dt,
                                                 float* __restrict__ Bg) {
    const int tile = blockIdx.x;          // 0..2047
    const int chain = tile >> 5;
    const int c = tile & 31;
    const int b = chain >> 4;
    const int h = chain & 15;
    const int tid = threadIdx.x;
    const int w = tid >> 6;
    const int l = tid & 63;

    __shared__ ushort_t Ks[CT * SP];
    __shared__ ushort_t Vs[CT * SP];
    __shared__ float bs[CT];

    {
        const int row = tid >> 2;
        const int seg = (tid & 3) * 16;
        const size_t grow = ((size_t)(b * SEQ + c * CT + row)) * QKVS + h * DHEAD + seg;
        float4 a0 = *(const float4*)&qkv[grow + 1024];      // k
        float4 a1 = *(const float4*)&qkv[grow + 1024 + 8];
        float4 b0 = *(const float4*)&qkv[grow + 2048];      // v
        float4 b1 = *(const float4*)&qkv[grow + 2048 + 8];
        *(float4*)&Ks[row * SP + seg]     = a0;
        *(float4*)&Ks[row * SP + seg + 8] = a1;
        *(float4*)&Vs[row * SP + seg]     = b0;
        *(float4*)&Vs[row * SP + seg + 8] = b1;
    }
    if (tid < 64) {
        float g = gate[((size_t)(b * SEQ + c * CT + tid)) * NHEADS + h];
        float lg = __logf(g);
#pragma unroll
        for (int d = 1; d < 64; d <<= 1) {
            float n = __shfl_up(lg, d, 64);
            if (l >= d) lg += n;
        }
        bs[tid] = lg;
        if (tid == 63) Bg[tile] = lg;
    }
    __syncthreads();

    const float B = bs[63];
    const int fr = l & 15;
    const int fq = (l >> 4) * 8;
    const int jw = w * 16;

    f32x4 accD[4];
#pragma unroll
    for (int nt = 0; nt < 4; ++nt)
#pragma unroll
        for (int r = 0; r < 4; ++r) accD[nt][r] = 0.f;

#pragma unroll
    for (int kc = 0; kc < 2; ++kc) {
        float ef[8];
#pragma unroll
        for (int m = 0; m < 8; ++m) ef[m] = __expf(B - bs[kc * 32 + fq + m]);
        bf16x8 va;
#pragma unroll
        for (int m = 0; m < 8; ++m)
            va[m] = (short)Vs[(kc * 32 + fq + m) * SP + jw + fr];
#pragma unroll
        for (int nt = 0; nt < 4; ++nt) {
            bf16x8 kf;
#pragma unroll
            for (int m = 0; m < 8; ++m)
                kf[m] = (short)f2bf(ef[m] * bf2f(Ks[(kc * 32 + fq + m) * SP + nt * 16 + fr]));
            accD[nt] = __builtin_amdgcn_mfma_f32_16x16x32_bf16(va, kf, accD[nt], 0, 0, 0);
        }
    }

    const int er = (l >> 4) * 4;
    const size_t dbase = (size_t)tile * (DHEAD * DHEAD);
#pragma unroll
    for (int nt = 0; nt < 4; ++nt)
#pragma unroll
        for (int r = 0; r < 4; ++r) {
            const int j = jw + er + r;
            const int i = nt * 16 + fr;
            Dt[dbase + j * DHEAD + i] = accD[nt][r];
        }
}

// ---------------------------------------------------------------------------
// Phase 2: sequential over 32 chunks; St[c] = state BEFORE chunk c (bf16,[j][i])
// ---------------------------------------------------------------------------
__global__ __launch_bounds__(256) void p2_kernel(const float* __restrict__ Dt,
                                                 const float* __restrict__ Bg,
                                                 ushort_t* __restrict__ St) {
    const int chain = blockIdx.x >> 2;
    const int jq = (blockIdx.x & 3) * 16;
    const int tid = threadIdx.x;
    const int jj = jq + (tid >> 4);
    const int ii = (tid & 15) * 4;

    float4 S = make_float4(0.f, 0.f, 0.f, 0.f);
    for (int c = 0; c < NC; ++c) {
        const size_t base = (((size_t)chain * NC + c) * DHEAD + jj) * DHEAD + ii;
        ushort4 o;
        o.x = f2bf(S.x); o.y = f2bf(S.y); o.z = f2bf(S.z); o.w = f2bf(S.w);
        *(ushort4*)&St[base] = o;
        const float eB = __expf(Bg[chain * NC + c]);
        const float4 D = *(const float4*)&Dt[base];
        S.x = eB * S.x + D.x;
        S.y = eB * S.y + D.y;
        S.z = eB * S.z + D.z;
        S.w = eB * S.w + D.w;
    }
}

// ---------------------------------------------------------------------------
// Phase 3: Y = diag(e^{b_t}) (Q@St) + (QK^T ⊙ decay ⊙ mask) @ V   -> yb bf16
// ---------------------------------------------------------------------------
__global__ __launch_bounds__(256) void p3_kernel(const ushort_t* __restrict__ qkv,
                                                 const ushort_t* __restrict__ St,
                                                 const float* __restrict__ gate,
                                                 ushort_t* __restrict__ yb) {
    const int tile = blockIdx.x;
    const int chain = tile >> 5;
    const int c = tile & 31;
    const int b = chain >> 4;
    const int h = chain & 15;
    const int tid = threadIdx.x;
    const int w = tid >> 6;
    const int l = tid & 63;

    __shared__ ushort_t Qs[CT * SP];
    __shared__ ushort_t Ks[CT * SP];
    __shared__ ushort_t Vs[CT * SP];
    __shared__ ushort_t Ss[CT * SP];
    __shared__ ushort_t Ps[CT * SP];
    __shared__ float bs[CT];

    {
        const int row = tid >> 2;
        const int seg = (tid & 3) * 16;
        const size_t grow = ((size_t)(b * SEQ + c * CT + row)) * QKVS + h * DHEAD + seg;
        float4 q0 = *(const float4*)&qkv[grow];
        float4 q1 = *(const float4*)&qkv[grow + 8];
        float4 k0 = *(const float4*)&qkv[grow + 1024];
        float4 k1 = *(const float4*)&qkv[grow + 1024 + 8];
        float4 v0 = *(const float4*)&qkv[grow + 2048];
        float4 v1 = *(const float4*)&qkv[grow + 2048 + 8];
        const size_t srow = (((size_t)chain * NC + c) * DHEAD + row) * DHEAD + seg;
        float4 s0 = *(const float4*)&St[srow];
        float4 s1 = *(const float4*)&St[srow + 8];
        *(float4*)&Qs[row * SP + seg]     = q0;
        *(float4*)&Qs[row * SP + seg + 8] = q1;
        *(float4*)&Ks[row * SP + seg]     = k0;
        *(float4*)&Ks[row * SP + seg + 8] = k1;
        *(float4*)&Vs[row * SP + seg]     = v0;
        *(float4*)&Vs[row * SP + seg + 8] = v1;
        *(float4*)&Ss[row * SP + seg]     = s0;
        *(float4*)&Ss[row * SP + seg + 8] = s1;
    }
    if (tid < 64) {
        float g = gate[((size_t)(b * SEQ + c * CT + tid)) * NHEADS + h];
        float lg = __logf(g);
#pragma unroll
        for (int d = 1; d < 64; d <<= 1) {
            float n = __shfl_up(lg, d, 64);
            if (l >= d) lg += n;
        }
        bs[tid] = lg;
    }
    __syncthreads();

    const int fr = l & 15;
    const int fq = (l >> 4) * 8;
    const int tw = w * 16;

    bf16x8 qa[2];
#pragma unroll
    for (int kc = 0; kc < 2; ++kc)
        qa[kc] = *(const bf16x8*)&Qs[(tw + fr) * SP + kc * 32 + fq];

    f32x4 accA[4], accP[4];
#pragma unroll
    for (int nt = 0; nt < 4; ++nt)
#pragma unroll
        for (int r = 0; r < 4; ++r) { accA[nt][r] = 0.f; accP[nt][r] = 0.f; }

#pragma unroll
    for (int kc = 0; kc < 2; ++kc)
#pragma unroll
        for (int nt = 0; nt < 4; ++nt) {
            bf16x8 sb = *(const bf16x8*)&Ss[(nt * 16 + fr) * SP + kc * 32 + fq];
            accA[nt] = __builtin_amdgcn_mfma_f32_16x16x32_bf16(qa[kc], sb, accA[nt], 0, 0, 0);
            bf16x8 kf = *(const bf16x8*)&Ks[(nt * 16 + fr) * SP + kc * 32 + fq];
            accP[nt] = __builtin_amdgcn_mfma_f32_16x16x32_bf16(qa[kc], kf, accP[nt], 0, 0, 0);
        }

    const int er = (l >> 4) * 4;
    int trow[4];
    float bt[4];
#pragma unroll
    for (int r = 0; r < 4; ++r) { trow[r] = tw + er + r; bt[r] = bs[trow[r]]; }
#pragma unroll
    for (int nt = 0; nt < 4; ++nt) {
        const int tau = nt * 16 + fr;
        const float btau = bs[tau];
#pragma unroll
        for (int r = 0; r < 4; ++r) {
            float f = (tau <= trow[r]) ? __expf(bt[r] - btau) : 0.f;
            Ps[trow[r] * SP + tau] = f2bf(accP[nt][r] * f);
        }
    }
    __syncthreads();

    f32x4 accY[4];
#pragma unroll
    for (int r = 0; r < 4; ++r) {
        const float eb = __expf(bt[r]);
#pragma unroll
        for (int nt = 0; nt < 4; ++nt) accY[nt][r] = accA[nt][r] * eb;
    }
#pragma unroll
    for (int kc = 0; kc < 2; ++kc) {
        bf16x8 pa = *(const bf16x8*)&Ps[(tw + fr) * SP + kc * 32 + fq];
#pragma unroll
        for (int nt = 0; nt < 4; ++nt) {
            bf16x8 vf;
#pragma unroll
            for (int m = 0; m < 8; ++m)
                vf[m] = (short)Vs[(kc * 32 + fq + m) * SP + nt * 16 + fr];
            accY[nt] = __builtin_amdgcn_mfma_f32_16x16x32_bf16(pa, vf, accY[nt], 0, 0, 0);
        }
    }

    const size_t ybase = ((size_t)(b * SEQ + c * CT)) * DMODEL + h * DHEAD;
#pragma unroll
    for (int nt = 0; nt < 4; ++nt)
#pragma unroll
        for (int r = 0; r < 4; ++r)
            yb[ybase + (size_t)trow[r] * DMODEL + nt * 16 + fr] = f2bf(accY[nt][r]);
}

// ---------------------------------------------------------------------------
// Host launch
// ---------------------------------------------------------------------------
extern "C" void kernel_launch(void* const* d_in, const int* in_sizes, int n_in,
                              void* d_out, int out_size, void* d_ws, size_t ws_size,
                              hipStream_t stream) {
    const float* x  = (const float*)d_in[0];
    const float* Wq = (const float*)d_in[1];
    const float* Wk = (const float*)d_in[2];
    const float* Wv = (const float*)d_in[3];
    const float* Wo = (const float*)d_in[4];
    const float* Wg = (const float*)d_in[5];
    const float* bg = (const float*)d_in[6];
    float* out = (float*)d_out;

    const size_t elems = (size_t)MTOK * DMODEL;     // 8,388,608
    const size_t welems = (size_t)DMODEL * DMODEL;  // 1,048,576
    const size_t stelems = (size_t)NCHAIN * NC * DHEAD * DHEAD;   // 8,388,608

    // layout with aliasing:
    // [xb | St (after p2)] [qkv] [wcat 4W] [gate f32] [Bg f32] [Dt f32 | yb (after p2)]
    ushort_t* xb   = (ushort_t*)d_ws;
    ushort_t* St   = xb;                            // alias: xb dead after QKV gemm
    ushort_t* qkv  = xb + elems;                    // [8192][3072]
    ushort_t* wcat = qkv + (size_t)MTOK * QKVS;     // rows: Wq,Wk,Wv,Wo
    float* gate    = (float*)(wcat + 4 * welems);
    float* Bg      = gate + (size_t)MTOK * NHEADS;
    float* Dt      = Bg + (size_t)NCHAIN * NC;
    ushort_t* yb   = (ushort_t*)Dt;                 // alias: Dt dead after p2

    const size_t need = (size_t)((char*)(Dt + stelems) - (char*)d_ws);  // ~105 MB
    if (ws_size < need) return;

    // converts (2 launches)
    cvt_f32_bf16<<<dim3((int)(elems / 4 / 256)), dim3(256), 0, stream>>>(x, xb, (int)(elems / 4));
    cvt_weights<<<dim3((int)(4 * welems / 4 / 256)), dim3(256), 0, stream>>>(Wq, Wk, Wv, Wo, wcat);

    // fused QKV projection: N=3072, epilogue per column range
    gemm_bf16<<<dim3(QKVS / GT, MTOK / GT), dim3(256), 0, stream>>>(
        xb, wcat, nullptr, qkv, MTOK, QKVS, DMODEL, 3);

    gate_kernel<<<dim3(MTOK), dim3(256), 0, stream>>>(x, Wg, bg, gate);

    // chunked linear-attention scan
    p1_kernel<<<dim3(NCHAIN * NC), dim3(256), 0, stream>>>(qkv, gate, Dt, Bg);
    p2_kernel<<<dim3(NCHAIN * 4), dim3(256), 0, stream>>>(Dt, Bg, St);
    p3_kernel<<<dim3(NCHAIN * NC), dim3(256), 0, stream>>>(qkv, St, gate, yb);

    // output projection (fp32 out)
    gemm_bf16<<<dim3(DMODEL / GT, MTOK / GT), dim3(256), 0, stream>>>(
        yb, wcat + 3 * welems, out, nullptr, MTOK, DMODEL, DMODEL, 0);
}